// Round 10
// baseline (224.037 us; speedup 1.0000x reference)
//
#include <hip/hip_runtime.h>
#include <stdint.h>

#define N_NODES 20000
#define N_EDGES 320000
#define K_MIX 5
#define IN_F 256
#define OUT_F 128
#define NT 11              /* 1 + 2K column tiles of 128 */
#define TC (NT * OUT_F)    /* 1408 */
#define BSTRIDE 96         /* bucket slots per node; max deg ~40 (Poisson 16) */

typedef __attribute__((ext_vector_type(8))) short short8;
typedef __attribute__((ext_vector_type(4))) float floatx4;

__device__ __forceinline__ float bf2f(unsigned int u) {
  union { unsigned int i; float f; } v;
  v.i = (u & 0xffffu) << 16;
  return v.f;
}
__device__ __forceinline__ unsigned short f2bf(float f) {
  union { float f; unsigned int i; } v;
  v.f = f;
  unsigned int x = v.i;
  unsigned int r = (x + 0x7fffu + ((x >> 16) & 1u)) >> 16;
  return (unsigned short)r;
}

// E[relu(X)], X ~ N(mu, sig) (sig is variance). Fast erf: A&S 7.1.26 reusing
// exp(-w^2/2) (== exp(-x^2) for x = w/sqrt2). |erf err| < 1.5e-7.
__device__ __forceinline__ float exrelu(float mu, float sig) {
  if (sig < 1e-30f) return fmaxf(mu, 0.f);
  float ss = sqrtf(sig);
  float w = mu / ss;
  float e = __expf(-0.5f * w * w);
  float axv = fabsf(w) * 0.70710678118654752f;
  float t = 1.f / (1.f + 0.3275911f * axv);
  float poly = t * (0.254829592f +
              t * (-0.284496736f +
              t * (1.421413741f +
              t * (-1.453152027f + t * 1.061405429f))));
  float erfv = 1.f - poly * e;
  erfv = copysignf(erfv, w);
  return ss * (e * 0.3989422804014327f + 0.5f * w * (1.f + erfv));
}

// async global->LDS 16B: wave-uniform LDS base, HW adds lane*16.
__device__ __forceinline__ void gll16(const void* g, void* l) {
  __builtin_amdgcn_global_load_lds(
      (const __attribute__((address_space(1))) void*)g,
      (__attribute__((address_space(3))) void*)l, 16, 0, 0);
}

// ---- bucket scatter: replaces deg + 3-kernel scan + CSR scatter -------------
// cursor[] (zeroed) doubles as the degree array after completion; neighbor
// lists live at bucket[r*BSTRIDE .. r*BSTRIDE+deg[r]). Weights (dinv products)
// are computed on the fly in k_spmm from final degrees.
__global__ void k_scatter(const int* __restrict__ row, const int* __restrict__ col,
                          int* __restrict__ cursor, int* __restrict__ bucket) {
  int t = blockIdx.x * 256 + threadIdx.x;
  if (t < N_EDGES) {
    int r = row[t];
    int p = atomicAdd(&cursor[r], 1);
    bucket[r * BSTRIDE + p] = col[t];
  }
}

// ---------------- B-matrix build: Bt[j][n][k] bf16 (transposed for MFMA B) ----
__global__ void k_buildB(const float* __restrict__ W, const float* __restrict__ means,
                         const float* __restrict__ logvars, unsigned short* __restrict__ Bt) {
  int idx = blockIdx.x * 256 + threadIdx.x;  // < 11*128*256
  int j = idx >> 15;
  int rem = idx & 32767;
  int n = rem >> 8;
  int kk = rem & 255;
  float wv = W[kk * OUT_F + n];
  float val;
  if (j == 0) val = wv;                                        // W
  else if (j <= 5) val = means[(j - 1) * IN_F + kk] * wv;      // means_k * W
  else val = expf(logvars[(j - 6) * IN_F + kk]) * wv * wv;     // var_k * W^2
  Bt[idx] = f2bf(val);
}

// ---- prep: pack x -> interleaved [clean bf16 x4 | nan-ind bf16 x4] + gamma ---
// Per node: 64 lanes x 8 ushorts (16B): clean values (NaN->0.0) then nan
// indicators (1.0 if NaN else 0.0). This makes the spmm inner loop pure FMA.
__global__ void k_prepx(const float* __restrict__ x, const float* __restrict__ logp,
                        const float* __restrict__ means, const float* __restrict__ logvars,
                        unsigned short* __restrict__ X0, float* __restrict__ gamma) {
  __shared__ float s_mean[K_MIX * IN_F];
  __shared__ float s_rv[K_MIX * IN_F];
  int t = threadIdx.x;
  for (int j = t; j < K_MIX * IN_F; j += 256) {
    s_mean[j] = means[j];
    s_rv[j] = expf(-logvars[j]);  // 1/var
  }
  __syncthreads();
  int node = blockIdx.x * 4 + (t >> 6);
  if (node >= N_NODES) return;
  int lane = t & 63;
  float4 xv = *(const float4*)(x + (size_t)node * IN_F + 4 * lane);
  float xf[4] = {xv.x, xv.y, xv.z, xv.w};
  float gsum[K_MIX] = {0, 0, 0, 0, 0};
  short8 o;
  unsigned short* op = (unsigned short*)&o;
#pragma unroll
  for (int j = 0; j < 4; j++) {
    bool nn = (xf[j] != xf[j]);
    op[j] = nn ? (unsigned short)0 : f2bf(xf[j]);       // clean value
    op[4 + j] = nn ? (unsigned short)0x3F80 : (unsigned short)0;  // 1.0 / 0.0
    if (!nn) {
      int fi = 4 * lane + j;
#pragma unroll
      for (int k = 0; k < K_MIX; k++) {
        float d = xf[j] - s_mean[k * IN_F + fi];
        gsum[k] += d * d * s_rv[k * IN_F + fi];
      }
    }
  }
  *(short8*)(X0 + (size_t)node * 512 + 8 * lane) = o;
#pragma unroll
  for (int k = 0; k < K_MIX; k++)
    for (int off = 32; off; off >>= 1) gsum[k] += __shfl_xor(gsum[k], off, 64);
  if (lane == 0) {
    float lg[K_MIX], mx = -1e30f;
#pragma unroll
    for (int k = 0; k < K_MIX; k++) {
      lg[k] = logp[k] - 0.5f * gsum[k];
      mx = fmaxf(mx, lg[k]);
    }
    float se = 0.f;
#pragma unroll
    for (int k = 0; k < K_MIX; k++) { lg[k] = expf(lg[k] - mx); se += lg[k]; }
    float inv = 1.f / se;
#pragma unroll
    for (int k = 0; k < K_MIX; k++) gamma[node * K_MIX + k] = lg[k] * inv;
  }
}

// ---- fused 3-way SpMM: A@x0 | A@m | A2@m  (one WAVE per node, 4 nodes/block) -
// Depth-8 pipeline, branch-free inner loop: the interleaved clean/nan-ind
// layout turns every step into 12 FMAs + 8 bf16 decodes per lane. Stale slots
// (W==0) contribute exactly 0 via fmaf(0, finite, acc) -> no guard needed.
// Weights dinv[r]*dinv[c] computed on the fly from bucket degrees.
__global__ __launch_bounds__(256) void k_spmm(const unsigned short* __restrict__ X0,
                       const int* __restrict__ deg, const int* __restrict__ bucket,
                       unsigned short* __restrict__ G, float* __restrict__ sArr) {
  int wvid = threadIdx.x >> 6;         // wave id within block (uniform per wave)
  int lane = threadIdx.x & 63;
  int node = __builtin_amdgcn_readfirstlane(blockIdx.x * 4 + wvid);
  int fo = 8 * lane;                   // interleaved record offset (ushorts)
  int go = 4 * lane;                   // G output offset (ushorts)
  float ax[4] = {0, 0, 0, 0}, am[4] = {0, 0, 0, 0}, am2[4] = {0, 0, 0, 0};
  float ssum = 0.f;
  int dv = __builtin_amdgcn_readfirstlane(deg[node]);
  float ds = rsqrtf((float)(dv + 1));  // dinv of self (+1 self-loop)
  float ws = ds * ds;
  int st = node * BSTRIDE;
  int total = dv + 1;                  // virtual idx 0 = self loop
  short8 zero8 = {0, 0, 0, 0, 0, 0, 0, 0};
  short8 B0 = zero8, B1 = zero8, B2 = zero8, B3 = zero8,
         B4 = zero8, B5 = zero8, B6 = zero8, B7 = zero8;
  float W0 = 0.f, W1 = 0.f, W2 = 0.f, W3 = 0.f,
        W4 = 0.f, W5 = 0.f, W6 = 0.f, W7 = 0.f;
  // prologue: fill slots with virtual idx 0..7
  B0 = *(const short8*)(X0 + (size_t)node * 512 + fo); W0 = ws;
#define PFILL(S)                                                      \
  if (S < total) {                                                    \
    int c = bucket[st + (S - 1)];                                     \
    W##S = ds * rsqrtf((float)(deg[c] + 1));                          \
    B##S = *(const short8*)(X0 + (size_t)c * 512 + fo);               \
  }
  PFILL(1) PFILL(2) PFILL(3) PFILL(4) PFILL(5) PFILL(6) PFILL(7)
#undef PFILL

#define STEP(S)                                                       \
  {                                                                   \
    float wvv = W##S, wv2 = wvv * wvv;                                \
    ssum += wvv;                                                      \
    const unsigned short* xp = (const unsigned short*)&B##S;          \
    _Pragma("unroll")                                                 \
    for (int j = 0; j < 4; j++) {                                     \
      float nf = bf2f(xp[4 + j]);                                     \
      ax[j] = fmaf(wvv, bf2f(xp[j]), ax[j]);                          \
      am[j] = fmaf(wvv, nf, am[j]);                                   \
      am2[j] = fmaf(wv2, nf, am2[j]);                                 \
    }                                                                 \
  }                                                                   \
  if (base + 8 + S < total) {                                         \
    int c = bucket[st + base + 7 + S];                                \
    W##S = ds * rsqrtf((float)(deg[c] + 1));                          \
    B##S = *(const short8*)(X0 + (size_t)c * 512 + fo);               \
  } else {                                                            \
    W##S = 0.f;                                                       \
  }

  for (int base = 0; base < total; base += 8) {
    STEP(0) STEP(1) STEP(2) STEP(3) STEP(4) STEP(5) STEP(6) STEP(7)
  }
#undef STEP

  ushort4 o;
  o.x = f2bf(ax[0]); o.y = f2bf(ax[1]); o.z = f2bf(ax[2]); o.w = f2bf(ax[3]);
  *(ushort4*)(G + node * 768 + go) = o;
  o.x = f2bf(am[0]); o.y = f2bf(am[1]); o.z = f2bf(am[2]); o.w = f2bf(am[3]);
  *(ushort4*)(G + node * 768 + 256 + go) = o;
  o.x = f2bf(am2[0]); o.y = f2bf(am2[1]); o.z = f2bf(am2[2]); o.w = f2bf(am2[3]);
  *(ushort4*)(G + node * 768 + 512 + go) = o;
  if (lane == 0) sArr[node] = ssum;
}

// ---- MFMA GEMM, LDS-staged (m97-style): T = (G slice) @ B_jt, bf16 out -------
// Staging via global_load_lds width-16; XOR swizzle applied to the GLOBAL
// source chunk so LDS contents match the register-staged original.
__global__ __launch_bounds__(256) void k_gemm(const unsigned short* __restrict__ G,
                                              const unsigned short* __restrict__ Bt,
                                              unsigned short* __restrict__ T) {
  __shared__ __align__(16) char Als[128 * 64 * 2];  // 16 KB
  __shared__ __align__(16) char Bls[128 * 64 * 2];  // 16 KB
  int mt = blockIdx.x, jt = blockIdx.y;
  int aoff = (jt == 0) ? 0 : (jt <= 5 ? 256 : 512);
  int t = threadIdx.x, w = t >> 6, lane = t & 63;
  int wr = w >> 1, wc = w & 1;
  int quad = lane >> 4, l16 = lane & 15;
  const unsigned short* Bp = Bt + (size_t)jt * 32768;

  floatx4 acc[4][4];
  floatx4 z = {0.f, 0.f, 0.f, 0.f};
#pragma unroll
  for (int mi = 0; mi < 4; mi++)
#pragma unroll
    for (int ni = 0; ni < 4; ni++) acc[mi][ni] = z;

  for (int k0 = 0; k0 < 256; k0 += 64) {
    __syncthreads();
#pragma unroll
    for (int i = 0; i < 4; i++) {
      int r = i * 32 + w * 8 + (lane >> 3);
      int c = (lane & 7) ^ (r & 7);
      int gr = mt * 128 + r;
      if (gr >= N_NODES) gr = N_NODES - 1;
      gll16(G + (size_t)gr * 768 + aoff + k0 + c * 8, Als + i * 4096 + w * 1024);
      gll16(Bp + (size_t)r * 256 + k0 + c * 8, Bls + i * 4096 + w * 1024);
    }
    __syncthreads();  // drains vmcnt(0): LDS-DMA complete for all waves
#pragma unroll
    for (int ks = 0; ks < 2; ks++) {
      int cc = ks * 4 + quad;
      short8 a[4], b[4];
#pragma unroll
      for (int mi = 0; mi < 4; mi++) {
        int r = wr * 64 + mi * 16 + l16;
        a[mi] = *(const short8*)(Als + r * 128 + (cc ^ (r & 7)) * 16);
      }
#pragma unroll
      for (int ni = 0; ni < 4; ni++) {
        int r = wc * 64 + ni * 16 + l16;
        b[ni] = *(const short8*)(Bls + r * 128 + (cc ^ (r & 7)) * 16);
      }
#pragma unroll
      for (int mi = 0; mi < 4; mi++)
#pragma unroll
        for (int ni = 0; ni < 4; ni++)
          acc[mi][ni] = __builtin_amdgcn_mfma_f32_16x16x32_bf16(a[mi], b[ni], acc[mi][ni], 0, 0, 0);
    }
  }
#pragma unroll
  for (int mi = 0; mi < 4; mi++)
#pragma unroll
    for (int ni = 0; ni < 4; ni++) {
      int gc = jt * 128 + wc * 64 + ni * 16 + l16;
#pragma unroll
      for (int reg = 0; reg < 4; reg++) {
        int gr = mt * 128 + wr * 64 + mi * 16 + quad * 4 + reg;
        if (gr < N_NODES) T[(size_t)gr * TC + gc] = f2bf(acc[mi][ni][reg]);
      }
    }
}

// ---------------- epilogue: Ex_relu + gamma-weighted combine ----------------
__global__ void k_final(const unsigned short* __restrict__ T, const float* __restrict__ gamma,
                        const float* __restrict__ sArr, const float* __restrict__ bias,
                        float* __restrict__ out) {
  int t = threadIdx.x;
  int node = blockIdx.x * 4 + (t >> 6);
  if (node >= N_NODES) return;
  int lane = t & 63;
  int o0 = 2 * lane;
  float g[K_MIX];
#pragma unroll
  for (int k = 0; k < K_MIX; k++) g[k] = gamma[node * K_MIX + k];
  float sv = sArr[node];
  float b0 = bias[o0], b1 = bias[o0 + 1];
  const unsigned short* Tr = T + (size_t)node * TC;
  unsigned int c0u = *(const unsigned int*)(Tr + o0);
  float cx0 = bf2f(c0u), cx1 = bf2f(c0u >> 16);
  float a0 = 0.f, a1 = 0.f;
#pragma unroll
  for (int k = 0; k < K_MIX; k++) {
    unsigned int tm = *(const unsigned int*)(Tr + 128 * (1 + k) + o0);
    unsigned int tv = *(const unsigned int*)(Tr + 128 * (6 + k) + o0);
    float mu0 = cx0 + bf2f(tm) + b0 * sv;
    float mu1 = cx1 + bf2f(tm >> 16) + b1 * sv;
    a0 += g[k] * exrelu(mu0, bf2f(tv));
    a1 += g[k] * exrelu(mu1, bf2f(tv >> 16));
  }
  float2 ov = {a0, a1};
  *(float2*)(out + (size_t)node * OUT_F + o0) = ov;
}

extern "C" void kernel_launch(void* const* d_in, const int* in_sizes, int n_in,
                              void* d_out, int out_size, void* d_ws, size_t ws_size,
                              hipStream_t stream) {
  const float* x = (const float*)d_in[0];
  const int* ei = (const int*)d_in[1];
  const float* logp = (const float*)d_in[2];
  const float* means = (const float*)d_in[3];
  const float* lvar = (const float*)d_in[4];
  const float* W = (const float*)d_in[5];
  const float* bias = (const float*)d_in[6];
  float* out = (float*)d_out;
  const int* row = ei;
  const int* col = ei + N_EDGES;

  char* p = (char*)d_ws;
  auto alloc = [&](size_t bytes) -> char* {
    char* q = p;
    p += (bytes + 255) & ~((size_t)255);
    return q;
  };
  int* cursor = (int*)alloc(N_NODES * 4);                 // becomes deg
  int* bucket = (int*)alloc((size_t)N_NODES * BSTRIDE * 4);
  float* gamma = (float*)alloc((size_t)N_NODES * K_MIX * 4);
  float* sArr = (float*)alloc(N_NODES * 4);
  unsigned short* Bt = (unsigned short*)alloc((size_t)NT * 128 * 256 * 2);
  unsigned short* X0 = (unsigned short*)alloc((size_t)N_NODES * 512 * 2);
  unsigned short* G = (unsigned short*)alloc((size_t)N_NODES * 768 * 2);
  unsigned short* T = (unsigned short*)alloc((size_t)N_NODES * TC * 2);

  hipMemsetAsync(cursor, 0, N_NODES * 4, stream);
  k_scatter<<<(N_EDGES + 255) / 256, 256, 0, stream>>>(row, col, cursor, bucket);
  k_buildB<<<(NT * 128 * 256) / 256, 256, 0, stream>>>(W, means, lvar, Bt);
  k_prepx<<<N_NODES / 4, 256, 0, stream>>>(x, logp, means, lvar, X0, gamma);
  k_spmm<<<N_NODES / 4, 256, 0, stream>>>(X0, cursor, bucket, G, sArr);
  k_gemm<<<dim3((N_NODES + 127) / 128, NT), 256, 0, stream>>>(G, Bt, T);
  k_final<<<N_NODES / 4, 256, 0, stream>>>(T, gamma, sArr, bias, out);
}

// Round 11
// 207.589 us; speedup vs baseline: 1.0792x; 1.0792x over previous
//
#include <hip/hip_runtime.h>
#include <stdint.h>

#define N_NODES 20000
#define N_EDGES 320000
#define K_MIX 5
#define IN_F 256
#define OUT_F 128
#define NT 11              /* 1 + 2K column tiles of 128 */
#define TC (NT * OUT_F)    /* 1408 */
#define BSTRIDE 96         /* bucket slots per node; max deg ~40 (Poisson 16) */
#define MT_TILES ((N_NODES + 127) / 128)   /* 157 */
#define GEMM_WGS (MT_TILES * NT)           /* 1727 */

typedef __attribute__((ext_vector_type(8))) short short8;
typedef __attribute__((ext_vector_type(4))) float floatx4;

__device__ __forceinline__ float bf2f(unsigned int u) {
  union { unsigned int i; float f; } v;
  v.i = (u & 0xffffu) << 16;
  return v.f;
}
__device__ __forceinline__ unsigned short f2bf(float f) {
  union { float f; unsigned int i; } v;
  v.f = f;
  unsigned int x = v.i;
  unsigned int r = (x + 0x7fffu + ((x >> 16) & 1u)) >> 16;
  return (unsigned short)r;
}

// E[relu(X)], X ~ N(mu, sig) (sig is variance). Fast erf: A&S 7.1.26 reusing
// exp(-w^2/2) (== exp(-x^2) for x = w/sqrt2). |erf err| < 1.5e-7.
__device__ __forceinline__ float exrelu(float mu, float sig) {
  if (sig < 1e-30f) return fmaxf(mu, 0.f);
  float ss = sqrtf(sig);
  float w = mu / ss;
  float e = __expf(-0.5f * w * w);
  float axv = fabsf(w) * 0.70710678118654752f;
  float t = 1.f / (1.f + 0.3275911f * axv);
  float poly = t * (0.254829592f +
              t * (-0.284496736f +
              t * (1.421413741f +
              t * (-1.453152027f + t * 1.061405429f))));
  float erfv = 1.f - poly * e;
  erfv = copysignf(erfv, w);
  return ss * (e * 0.3989422804014327f + 0.5f * w * (1.f + erfv));
}

// async global->LDS 16B: wave-uniform LDS base, HW adds lane*16.
__device__ __forceinline__ void gll16(const void* g, void* l) {
  __builtin_amdgcn_global_load_lds(
      (const __attribute__((address_space(1))) void*)g,
      (__attribute__((address_space(3))) void*)l, 16, 0, 0);
}

// ---- bucket scatter: cursor[] (zeroed) becomes the degree array -------------
__global__ void k_scatter(const int* __restrict__ row, const int* __restrict__ col,
                          int* __restrict__ cursor, int* __restrict__ bucket) {
  int t = blockIdx.x * 256 + threadIdx.x;
  if (t < N_EDGES) {
    int r = row[t];
    int p = atomicAdd(&cursor[r], 1);
    bucket[r * BSTRIDE + p] = col[t];
  }
}

// ---------------- B-matrix build: Bt[j][n][k] bf16 (transposed for MFMA B) ----
__global__ void k_buildB(const float* __restrict__ W, const float* __restrict__ means,
                         const float* __restrict__ logvars, unsigned short* __restrict__ Bt) {
  int idx = blockIdx.x * 256 + threadIdx.x;  // < 11*128*256
  int j = idx >> 15;
  int rem = idx & 32767;
  int n = rem >> 8;
  int kk = rem & 255;
  float wv = W[kk * OUT_F + n];
  float val;
  if (j == 0) val = wv;                                        // W
  else if (j <= 5) val = means[(j - 1) * IN_F + kk] * wv;      // means_k * W
  else val = expf(logvars[(j - 6) * IN_F + kk]) * wv * wv;     // var_k * W^2
  Bt[idx] = f2bf(val);
}

// ---- prep: clean bf16 X0 (NaN->0) + 1-byte nan sidecar + gamma ---------------
// Xn[node*64+lane] bits 0..3 = nan flags for the lane's 4 features.
__global__ void k_prepx(const float* __restrict__ x, const float* __restrict__ logp,
                        const float* __restrict__ means, const float* __restrict__ logvars,
                        unsigned short* __restrict__ X0, unsigned char* __restrict__ Xn,
                        float* __restrict__ gamma) {
  __shared__ float s_mean[K_MIX * IN_F];
  __shared__ float s_rv[K_MIX * IN_F];
  int t = threadIdx.x;
  for (int j = t; j < K_MIX * IN_F; j += 256) {
    s_mean[j] = means[j];
    s_rv[j] = expf(-logvars[j]);  // 1/var
  }
  __syncthreads();
  int node = blockIdx.x * 4 + (t >> 6);
  if (node >= N_NODES) return;
  int lane = t & 63;
  float4 xv = *(const float4*)(x + (size_t)node * IN_F + 4 * lane);
  float xf[4] = {xv.x, xv.y, xv.z, xv.w};
  float gsum[K_MIX] = {0, 0, 0, 0, 0};
  ushort4 o;
  unsigned short* op = (unsigned short*)&o;
  unsigned int nb = 0;
#pragma unroll
  for (int j = 0; j < 4; j++) {
    bool nn = (xf[j] != xf[j]);
    op[j] = nn ? (unsigned short)0 : f2bf(xf[j]);  // clean value (NaN -> 0)
    if (nn) nb |= (1u << j);
    if (!nn) {
      int fi = 4 * lane + j;
#pragma unroll
      for (int k = 0; k < K_MIX; k++) {
        float d = xf[j] - s_mean[k * IN_F + fi];
        gsum[k] += d * d * s_rv[k * IN_F + fi];
      }
    }
  }
  *(ushort4*)(X0 + (size_t)node * IN_F + 4 * lane) = o;
  Xn[node * 64 + lane] = (unsigned char)nb;
#pragma unroll
  for (int k = 0; k < K_MIX; k++)
    for (int off = 32; off; off >>= 1) gsum[k] += __shfl_xor(gsum[k], off, 64);
  if (lane == 0) {
    float lg[K_MIX], mx = -1e30f;
#pragma unroll
    for (int k = 0; k < K_MIX; k++) {
      lg[k] = logp[k] - 0.5f * gsum[k];
      mx = fmaxf(mx, lg[k]);
    }
    float se = 0.f;
#pragma unroll
    for (int k = 0; k < K_MIX; k++) { lg[k] = expf(lg[k] - mx); se += lg[k]; }
    float inv = 1.f / se;
#pragma unroll
    for (int k = 0; k < K_MIX; k++) gamma[node * K_MIX + k] = lg[k] * inv;
  }
}

// ---- fused 3-way SpMM: A@x0 | A@m | A2@m  (one WAVE per node, 4 nodes/block) -
// Depth-8 pipeline. Clean-value + nan-byte encoding: inner step is 3 fmaf +
// bfe/cvt per element -- no compares/cndmask chains. Gather = 512B values +
// 64B nan bytes per wave-step (vs R10's 1KB, which blew FETCH 62->143MB).
// Bit-identical to the marker version: wv*n (n in {0,1}) == (nn?wv:0).
__global__ __launch_bounds__(256) void k_spmm(const unsigned short* __restrict__ X0,
                       const unsigned char* __restrict__ Xn,
                       const int* __restrict__ deg, const int* __restrict__ bucket,
                       unsigned short* __restrict__ G, float* __restrict__ sArr) {
  int wvid = threadIdx.x >> 6;         // wave id within block (uniform per wave)
  int lane = threadIdx.x & 63;
  int node = __builtin_amdgcn_readfirstlane(blockIdx.x * 4 + wvid);
  int fo = 4 * lane;
  float ax[4] = {0, 0, 0, 0}, am[4] = {0, 0, 0, 0}, am2[4] = {0, 0, 0, 0};
  float ssum = 0.f;
  int dv = __builtin_amdgcn_readfirstlane(deg[node]);
  float ds = rsqrtf((float)(dv + 1));  // dinv of self (+1 self-loop)
  float ws = ds * ds;
  int st = node * BSTRIDE;
  int total = dv + 1;                  // virtual idx 0 = self loop
  ushort4 zero4 = {0, 0, 0, 0};
  ushort4 B0 = zero4, B1 = zero4, B2 = zero4, B3 = zero4,
          B4 = zero4, B5 = zero4, B6 = zero4, B7 = zero4;
  unsigned int M0 = 0, M1 = 0, M2 = 0, M3 = 0, M4 = 0, M5 = 0, M6 = 0, M7 = 0;
  float W0 = 0.f, W1 = 0.f, W2 = 0.f, W3 = 0.f,
        W4 = 0.f, W5 = 0.f, W6 = 0.f, W7 = 0.f;
  // prologue: fill slots with virtual idx 0..7
  B0 = *(const ushort4*)(X0 + (size_t)node * IN_F + fo);
  M0 = Xn[node * 64 + lane];
  W0 = ws;
#define PFILL(S)                                                      \
  if (S < total) {                                                    \
    int c = bucket[st + (S - 1)];                                     \
    W##S = ds * rsqrtf((float)(deg[c] + 1));                          \
    B##S = *(const ushort4*)(X0 + (size_t)c * IN_F + fo);             \
    M##S = Xn[c * 64 + lane];                                         \
  }
  PFILL(1) PFILL(2) PFILL(3) PFILL(4) PFILL(5) PFILL(6) PFILL(7)
#undef PFILL

#define STEP(S)                                                       \
  if (W##S != 0.f) {                                                  \
    float wvv = W##S, wv2 = wvv * wvv;                                \
    ssum += wvv;                                                      \
    const unsigned short* xp = (const unsigned short*)&B##S;          \
    unsigned int mb = M##S;                                           \
    _Pragma("unroll")                                                 \
    for (int j = 0; j < 4; j++) {                                     \
      float nf = (float)((mb >> j) & 1u);                             \
      ax[j] = fmaf(wvv, bf2f(xp[j]), ax[j]);                          \
      am[j] = fmaf(wvv, nf, am[j]);                                   \
      am2[j] = fmaf(wv2, nf, am2[j]);                                 \
    }                                                                 \
  }                                                                   \
  if (base + 8 + S < total) {                                         \
    int c = bucket[st + base + 7 + S];                                \
    W##S = ds * rsqrtf((float)(deg[c] + 1));                          \
    B##S = *(const ushort4*)(X0 + (size_t)c * IN_F + fo);             \
    M##S = Xn[c * 64 + lane];                                         \
  } else {                                                            \
    W##S = 0.f;                                                       \
  }

  for (int base = 0; base < total; base += 8) {
    STEP(0) STEP(1) STEP(2) STEP(3) STEP(4) STEP(5) STEP(6) STEP(7)
  }
#undef STEP

  ushort4 o;
  o.x = f2bf(ax[0]); o.y = f2bf(ax[1]); o.z = f2bf(ax[2]); o.w = f2bf(ax[3]);
  *(ushort4*)(G + node * 768 + fo) = o;
  o.x = f2bf(am[0]); o.y = f2bf(am[1]); o.z = f2bf(am[2]); o.w = f2bf(am[3]);
  *(ushort4*)(G + node * 768 + 256 + fo) = o;
  o.x = f2bf(am2[0]); o.y = f2bf(am2[1]); o.z = f2bf(am2[2]); o.w = f2bf(am2[3]);
  *(ushort4*)(G + node * 768 + 512 + fo) = o;
  if (lane == 0) sArr[node] = ssum;
}

// ---- MFMA GEMM, LDS-staged (m97-style): T = (G slice) @ B_jt, bf16 out -------
// global_load_lds width-16 staging (swizzle on the GLOBAL source chunk).
// XCD-aware bijective remap (T1/m204): all 11 jt-tiles of one mt land on the
// same XCD's L2, temporally adjacent -> A-slice re-reads (x5) become L2 hits.
__global__ __launch_bounds__(256) void k_gemm(const unsigned short* __restrict__ G,
                                              const unsigned short* __restrict__ Bt,
                                              unsigned short* __restrict__ T) {
  __shared__ __align__(16) char Als[128 * 64 * 2];  // 16 KB
  __shared__ __align__(16) char Bls[128 * 64 * 2];  // 16 KB
  // bijective XCD chunk map: q=GEMM_WGS/8, r=GEMM_WGS%8
  int linear = blockIdx.x;
  const int q = GEMM_WGS / 8, r = GEMM_WGS % 8;
  int xcd = linear & 7, ixd = linear >> 3;
  int orig = (xcd < r ? xcd * (q + 1) : r * (q + 1) + (xcd - r) * q) + ixd;
  int mt = orig / NT, jt = orig - mt * NT;
  int aoff = (jt == 0) ? 0 : (jt <= 5 ? 256 : 512);
  int t = threadIdx.x, w = t >> 6, lane = t & 63;
  int wr = w >> 1, wc = w & 1;
  int quad = lane >> 4, l16 = lane & 15;
  const unsigned short* Bp = Bt + (size_t)jt * 32768;

  floatx4 acc[4][4];
  floatx4 z = {0.f, 0.f, 0.f, 0.f};
#pragma unroll
  for (int mi = 0; mi < 4; mi++)
#pragma unroll
    for (int ni = 0; ni < 4; ni++) acc[mi][ni] = z;

  for (int k0 = 0; k0 < 256; k0 += 64) {
    __syncthreads();
#pragma unroll
    for (int i = 0; i < 4; i++) {
      int rr = i * 32 + w * 8 + (lane >> 3);
      int c = (lane & 7) ^ (rr & 7);
      int gr = mt * 128 + rr;
      if (gr >= N_NODES) gr = N_NODES - 1;
      gll16(G + (size_t)gr * 768 + aoff + k0 + c * 8, Als + i * 4096 + w * 1024);
      gll16(Bp + (size_t)rr * 256 + k0 + c * 8, Bls + i * 4096 + w * 1024);
    }
    __syncthreads();  // drains vmcnt(0): LDS-DMA complete for all waves
#pragma unroll
    for (int ks = 0; ks < 2; ks++) {
      int cc = ks * 4 + quad;
      short8 a[4], b[4];
#pragma unroll
      for (int mi = 0; mi < 4; mi++) {
        int rr = wr * 64 + mi * 16 + l16;
        a[mi] = *(const short8*)(Als + rr * 128 + (cc ^ (rr & 7)) * 16);
      }
#pragma unroll
      for (int ni = 0; ni < 4; ni++) {
        int rr = wc * 64 + ni * 16 + l16;
        b[ni] = *(const short8*)(Bls + rr * 128 + (cc ^ (rr & 7)) * 16);
      }
#pragma unroll
      for (int mi = 0; mi < 4; mi++)
#pragma unroll
        for (int ni = 0; ni < 4; ni++)
          acc[mi][ni] = __builtin_amdgcn_mfma_f32_16x16x32_bf16(a[mi], b[ni], acc[mi][ni], 0, 0, 0);
    }
  }
#pragma unroll
  for (int mi = 0; mi < 4; mi++)
#pragma unroll
    for (int ni = 0; ni < 4; ni++) {
      int gc = jt * 128 + wc * 64 + ni * 16 + l16;
#pragma unroll
      for (int reg = 0; reg < 4; reg++) {
        int gr = mt * 128 + wr * 64 + mi * 16 + quad * 4 + reg;
        if (gr < N_NODES) T[(size_t)gr * TC + gc] = f2bf(acc[mi][ni][reg]);
      }
    }
}

// ---------------- epilogue: Ex_relu + gamma-weighted combine ----------------
__global__ void k_final(const unsigned short* __restrict__ T, const float* __restrict__ gamma,
                        const float* __restrict__ sArr, const float* __restrict__ bias,
                        float* __restrict__ out) {
  int t = threadIdx.x;
  int node = blockIdx.x * 4 + (t >> 6);
  if (node >= N_NODES) return;
  int lane = t & 63;
  int o0 = 2 * lane;
  float g[K_MIX];
#pragma unroll
  for (int k = 0; k < K_MIX; k++) g[k] = gamma[node * K_MIX + k];
  float sv = sArr[node];
  float b0 = bias[o0], b1 = bias[o0 + 1];
  const unsigned short* Tr = T + (size_t)node * TC;
  unsigned int c0u = *(const unsigned int*)(Tr + o0);
  float cx0 = bf2f(c0u), cx1 = bf2f(c0u >> 16);
  float a0 = 0.f, a1 = 0.f;
#pragma unroll
  for (int k = 0; k < K_MIX; k++) {
    unsigned int tm = *(const unsigned int*)(Tr + 128 * (1 + k) + o0);
    unsigned int tv = *(const unsigned int*)(Tr + 128 * (6 + k) + o0);
    float mu0 = cx0 + bf2f(tm) + b0 * sv;
    float mu1 = cx1 + bf2f(tm >> 16) + b1 * sv;
    a0 += g[k] * exrelu(mu0, bf2f(tv));
    a1 += g[k] * exrelu(mu1, bf2f(tv >> 16));
  }
  float2 ov = {a0, a1};
  *(float2*)(out + (size_t)node * OUT_F + o0) = ov;
}

extern "C" void kernel_launch(void* const* d_in, const int* in_sizes, int n_in,
                              void* d_out, int out_size, void* d_ws, size_t ws_size,
                              hipStream_t stream) {
  const float* x = (const float*)d_in[0];
  const int* ei = (const int*)d_in[1];
  const float* logp = (const float*)d_in[2];
  const float* means = (const float*)d_in[3];
  const float* lvar = (const float*)d_in[4];
  const float* W = (const float*)d_in[5];
  const float* bias = (const float*)d_in[6];
  float* out = (float*)d_out;
  const int* row = ei;
  const int* col = ei + N_EDGES;

  char* p = (char*)d_ws;
  auto alloc = [&](size_t bytes) -> char* {
    char* q = p;
    p += (bytes + 255) & ~((size_t)255);
    return q;
  };
  int* cursor = (int*)alloc(N_NODES * 4);                 // becomes deg
  int* bucket = (int*)alloc((size_t)N_NODES * BSTRIDE * 4);
  float* gamma = (float*)alloc((size_t)N_NODES * K_MIX * 4);
  float* sArr = (float*)alloc(N_NODES * 4);
  unsigned short* Bt = (unsigned short*)alloc((size_t)NT * 128 * 256 * 2);
  unsigned short* X0 = (unsigned short*)alloc((size_t)N_NODES * IN_F * 2);
  unsigned char* Xn = (unsigned char*)alloc((size_t)N_NODES * 64);
  unsigned short* G = (unsigned short*)alloc((size_t)N_NODES * 768 * 2);
  unsigned short* T = (unsigned short*)alloc((size_t)N_NODES * TC * 2);

  hipMemsetAsync(cursor, 0, N_NODES * 4, stream);
  k_scatter<<<(N_EDGES + 255) / 256, 256, 0, stream>>>(row, col, cursor, bucket);
  k_buildB<<<(NT * 128 * 256) / 256, 256, 0, stream>>>(W, means, lvar, Bt);
  k_prepx<<<N_NODES / 4, 256, 0, stream>>>(x, logp, means, lvar, X0, Xn, gamma);
  k_spmm<<<N_NODES / 4, 256, 0, stream>>>(X0, Xn, cursor, bucket, G, sArr);
  k_gemm<<<GEMM_WGS, 256, 0, stream>>>(G, Bt, T);
  k_final<<<N_NODES / 4, 256, 0, stream>>>(T, gamma, sArr, bias, out);
}

// Round 12
// 198.187 us; speedup vs baseline: 1.1304x; 1.0474x over previous
//
#include <hip/hip_runtime.h>
#include <stdint.h>

#define N_NODES 20000
#define N_EDGES 320000
#define K_MIX 5
#define IN_F 256
#define OUT_F 128
#define NT 11              /* 1 + 2K column tiles of 128 */
#define TC (NT * OUT_F)    /* 1408 */
#define BSTRIDE 96         /* bucket slots per node; max deg ~40 (Poisson 16) */
#define MT_TILES ((N_NODES + 127) / 128)   /* 157 */
#define GEMM_WGS (MT_TILES * NT)           /* 1727 */

typedef __attribute__((ext_vector_type(8))) short short8;
typedef __attribute__((ext_vector_type(4))) float floatx4;

__device__ __forceinline__ float bf2f(unsigned int u) {
  union { unsigned int i; float f; } v;
  v.i = (u & 0xffffu) << 16;
  return v.f;
}
__device__ __forceinline__ unsigned short f2bf(float f) {
  union { float f; unsigned int i; } v;
  v.f = f;
  unsigned int x = v.i;
  unsigned int r = (x + 0x7fffu + ((x >> 16) & 1u)) >> 16;
  return (unsigned short)r;
}

// E[relu(X)], X ~ N(mu, sig) (sig is variance). Fast erf: A&S 7.1.26 reusing
// exp(-w^2/2) (== exp(-x^2) for x = w/sqrt2). |erf err| < 1.5e-7.
__device__ __forceinline__ float exrelu(float mu, float sig) {
  if (sig < 1e-30f) return fmaxf(mu, 0.f);
  float ss = sqrtf(sig);
  float w = mu / ss;
  float e = __expf(-0.5f * w * w);
  float axv = fabsf(w) * 0.70710678118654752f;
  float t = 1.f / (1.f + 0.3275911f * axv);
  float poly = t * (0.254829592f +
              t * (-0.284496736f +
              t * (1.421413741f +
              t * (-1.453152027f + t * 1.061405429f))));
  float erfv = 1.f - poly * e;
  erfv = copysignf(erfv, w);
  return ss * (e * 0.3989422804014327f + 0.5f * w * (1.f + erfv));
}

// async global->LDS 16B: wave-uniform LDS base, HW adds lane*16.
__device__ __forceinline__ void gll16(const void* g, void* l) {
  __builtin_amdgcn_global_load_lds(
      (const __attribute__((address_space(1))) void*)g,
      (__attribute__((address_space(3))) void*)l, 16, 0, 0);
}

__device__ __forceinline__ float readlane_f(float v, int l) {
  return __int_as_float(__builtin_amdgcn_readlane(__float_as_int(v), l));
}

// ---- bucket scatter: cursor[] (zeroed) becomes the degree array -------------
__global__ void k_scatter(const int* __restrict__ row, const int* __restrict__ col,
                          int* __restrict__ cursor, int* __restrict__ bucket) {
  int t = blockIdx.x * 256 + threadIdx.x;
  if (t < N_EDGES) {
    int r = row[t];
    int p = atomicAdd(&cursor[r], 1);
    bucket[r * BSTRIDE + p] = col[t];
  }
}

// ---------------- B-matrix build: Bt[j][n][k] bf16 (transposed for MFMA B) ----
__global__ void k_buildB(const float* __restrict__ W, const float* __restrict__ means,
                         const float* __restrict__ logvars, unsigned short* __restrict__ Bt) {
  int idx = blockIdx.x * 256 + threadIdx.x;  // < 11*128*256
  int j = idx >> 15;
  int rem = idx & 32767;
  int n = rem >> 8;
  int kk = rem & 255;
  float wv = W[kk * OUT_F + n];
  float val;
  if (j == 0) val = wv;                                        // W
  else if (j <= 5) val = means[(j - 1) * IN_F + kk] * wv;      // means_k * W
  else val = expf(logvars[(j - 6) * IN_F + kk]) * wv * wv;     // var_k * W^2
  Bt[idx] = f2bf(val);
}

// ---- prep: pack x -> bf16 X0 (NaN marker 0x7FC0 for missing) + gamma ---------
__global__ void k_prepx(const float* __restrict__ x, const float* __restrict__ logp,
                        const float* __restrict__ means, const float* __restrict__ logvars,
                        unsigned short* __restrict__ X0, float* __restrict__ gamma) {
  __shared__ float s_mean[K_MIX * IN_F];
  __shared__ float s_rv[K_MIX * IN_F];
  int t = threadIdx.x;
  for (int j = t; j < K_MIX * IN_F; j += 256) {
    s_mean[j] = means[j];
    s_rv[j] = expf(-logvars[j]);  // 1/var
  }
  __syncthreads();
  int node = blockIdx.x * 4 + (t >> 6);
  if (node >= N_NODES) return;
  int lane = t & 63;
  float4 xv = *(const float4*)(x + (size_t)node * IN_F + 4 * lane);
  float xf[4] = {xv.x, xv.y, xv.z, xv.w};
  float gsum[K_MIX] = {0, 0, 0, 0, 0};
  ushort4 o;
  unsigned short* op = (unsigned short*)&o;
#pragma unroll
  for (int j = 0; j < 4; j++) {
    bool nn = (xf[j] != xf[j]);
    op[j] = nn ? (unsigned short)0x7FC0 : f2bf(xf[j]);
    if (!nn) {
      int fi = 4 * lane + j;
#pragma unroll
      for (int k = 0; k < K_MIX; k++) {
        float d = xf[j] - s_mean[k * IN_F + fi];
        gsum[k] += d * d * s_rv[k * IN_F + fi];
      }
    }
  }
  *(ushort4*)(X0 + (size_t)node * IN_F + 4 * lane) = o;
#pragma unroll
  for (int k = 0; k < K_MIX; k++)
    for (int off = 32; off; off >>= 1) gsum[k] += __shfl_xor(gsum[k], off, 64);
  if (lane == 0) {
    float lg[K_MIX], mx = -1e30f;
#pragma unroll
    for (int k = 0; k < K_MIX; k++) {
      lg[k] = logp[k] - 0.5f * gsum[k];
      mx = fmaxf(mx, lg[k]);
    }
    float se = 0.f;
#pragma unroll
    for (int k = 0; k < K_MIX; k++) { lg[k] = expf(lg[k] - mx); se += lg[k]; }
    float inv = 1.f / se;
#pragma unroll
    for (int k = 0; k < K_MIX; k++) gamma[node * K_MIX + k] = lg[k] * inv;
  }
}

// ---- fused 3-way SpMM (one WAVE per node): register-resident edge metadata --
// Key change vs R8-R11: per-edge (col, weight) is preloaded ONCE into the
// wave's lanes (lane i = neighbor i; deg <= ~40 < 64) with two vector ops,
// then broadcast per step via v_readlane (register-only). The hot loop's ONLY
// memory op is the X0 gather -> vmcnt-counted FIFO pipelining actually works;
// the old per-step scalar bucket/deg loads forced s_waitcnt lgkmcnt(0) drains
// (SMEM returns out of order) that serialized the depth-8 pipeline.
// ssum comes from one shuffle-reduce of the lane weights. Self-loop processed
// first (preserves original summation order). Rare deg>63 tail: scalar path.
__global__ __launch_bounds__(256) void k_spmm(const unsigned short* __restrict__ X0,
                       const int* __restrict__ deg, const int* __restrict__ bucket,
                       unsigned short* __restrict__ G, float* __restrict__ sArr) {
  int wvid = threadIdx.x >> 6;         // wave id within block (uniform per wave)
  int lane = threadIdx.x & 63;
  int node = __builtin_amdgcn_readfirstlane(blockIdx.x * 4 + wvid);
  int fo = 4 * lane;
  int dv = __builtin_amdgcn_readfirstlane(deg[node]);
  float ds = rsqrtf((float)(dv + 1));  // dinv of self (+1 self-loop)
  float ws = ds * ds;

  // lane-distributed edge metadata: lane i < dv holds (col_i, w_i)
  int c_l = 0;
  float w_l = 0.f;
  if (lane < dv) {
    int c = bucket[node * BSTRIDE + lane];
    c_l = c;
    w_l = ds * rsqrtf((float)(deg[c] + 1));
  }
  float ssum = (lane == 0) ? ws : 0.f;
  ssum += w_l;
#pragma unroll
  for (int off = 32; off; off >>= 1) ssum += __shfl_xor(ssum, off, 64);

  float ax[4] = {0, 0, 0, 0}, am[4] = {0, 0, 0, 0}, am2[4] = {0, 0, 0, 0};

  // ---- self-loop first (matches original slot-0 ordering) ----
  {
    ushort4 Bs = *(const ushort4*)(X0 + (size_t)node * IN_F + fo);
    const unsigned short* xp = (const unsigned short*)&Bs;
#pragma unroll
    for (int j = 0; j < 4; j++) {
      float xf = bf2f(xp[j]);
      bool nn = (xf != xf);
      ax[j] = fmaf(ws, nn ? 0.f : xf, ax[j]);
      am[j] += nn ? ws : 0.f;
      am2[j] += nn ? ws * ws : 0.f;
    }
  }

  int te = (dv < 63) ? dv : 63;        // edges handled via lane-list
  ushort4 zero4 = {0, 0, 0, 0};
  ushort4 B0 = zero4, B1 = zero4, B2 = zero4, B3 = zero4,
          B4 = zero4, B5 = zero4, B6 = zero4, B7 = zero4;
  float W0 = 0.f, W1 = 0.f, W2 = 0.f, W3 = 0.f,
        W4 = 0.f, W5 = 0.f, W6 = 0.f, W7 = 0.f;
  // prologue: slots 0..7 = edges 0..7 (readlane broadcast, vector gather)
#define PFILL(S)                                                      \
  if (S < te) {                                                       \
    int c = __builtin_amdgcn_readlane(c_l, S);                        \
    W##S = readlane_f(w_l, S);                                        \
    B##S = *(const ushort4*)(X0 + (size_t)c * IN_F + fo);             \
  }
  PFILL(0) PFILL(1) PFILL(2) PFILL(3) PFILL(4) PFILL(5) PFILL(6) PFILL(7)
#undef PFILL

#define STEP(S)                                                       \
  {                                                                   \
    float wvv = W##S, wv2 = wvv * wvv;                                \
    const unsigned short* xp = (const unsigned short*)&B##S;          \
    _Pragma("unroll")                                                 \
    for (int j = 0; j < 4; j++) {                                     \
      float xf = bf2f(xp[j]);                                         \
      bool nn = (xf != xf);                                           \
      ax[j] = fmaf(wvv, nn ? 0.f : xf, ax[j]);                        \
      am[j] += nn ? wvv : 0.f;                                        \
      am2[j] += nn ? wv2 : 0.f;                                       \
    }                                                                 \
  }                                                                   \
  if (base + 8 + S < te) {                                            \
    int idx = base + 8 + S;                                           \
    int c = __builtin_amdgcn_readlane(c_l, idx);                      \
    W##S = readlane_f(w_l, idx);                                      \
    B##S = *(const ushort4*)(X0 + (size_t)c * IN_F + fo);             \
  } else {                                                            \
    W##S = 0.f;                                                       \
  }

  for (int base = 0; base < te; base += 8) {
    STEP(0) STEP(1) STEP(2) STEP(3) STEP(4) STEP(5) STEP(6) STEP(7)
  }
#undef STEP

  // rare tail (deg > 63): scalar path, practically never taken
  for (int i = 63; i < dv; ++i) {
    int c = bucket[node * BSTRIDE + i];
    float wvv = ds * rsqrtf((float)(deg[c] + 1));
    float wv2 = wvv * wvv;
    ushort4 Bt4 = *(const ushort4*)(X0 + (size_t)c * IN_F + fo);
    const unsigned short* xp = (const unsigned short*)&Bt4;
#pragma unroll
    for (int j = 0; j < 4; j++) {
      float xf = bf2f(xp[j]);
      bool nn = (xf != xf);
      ax[j] = fmaf(wvv, nn ? 0.f : xf, ax[j]);
      am[j] += nn ? wvv : 0.f;
      am2[j] += nn ? wv2 : 0.f;
    }
  }

  ushort4 o;
  o.x = f2bf(ax[0]); o.y = f2bf(ax[1]); o.z = f2bf(ax[2]); o.w = f2bf(ax[3]);
  *(ushort4*)(G + node * 768 + fo) = o;
  o.x = f2bf(am[0]); o.y = f2bf(am[1]); o.z = f2bf(am[2]); o.w = f2bf(am[3]);
  *(ushort4*)(G + node * 768 + 256 + fo) = o;
  o.x = f2bf(am2[0]); o.y = f2bf(am2[1]); o.z = f2bf(am2[2]); o.w = f2bf(am2[3]);
  *(ushort4*)(G + node * 768 + 512 + fo) = o;
  if (lane == 0) sArr[node] = ssum;
}

// ---- MFMA GEMM, LDS-staged (m97-style): T = (G slice) @ B_jt, bf16 out -------
// global_load_lds width-16 staging (swizzle on the GLOBAL source chunk).
// XCD-aware bijective remap (T1/m204): all 11 jt-tiles of one mt land on the
// same XCD's L2, temporally adjacent -> A-slice re-reads (x5) become L2 hits.
__global__ __launch_bounds__(256) void k_gemm(const unsigned short* __restrict__ G,
                                              const unsigned short* __restrict__ Bt,
                                              unsigned short* __restrict__ T) {
  __shared__ __align__(16) char Als[128 * 64 * 2];  // 16 KB
  __shared__ __align__(16) char Bls[128 * 64 * 2];  // 16 KB
  // bijective XCD chunk map: q=GEMM_WGS/8, r=GEMM_WGS%8
  int linear = blockIdx.x;
  const int q = GEMM_WGS / 8, r = GEMM_WGS % 8;
  int xcd = linear & 7, ixd = linear >> 3;
  int orig = (xcd < r ? xcd * (q + 1) : r * (q + 1) + (xcd - r) * q) + ixd;
  int mt = orig / NT, jt = orig - mt * NT;
  int aoff = (jt == 0) ? 0 : (jt <= 5 ? 256 : 512);
  int t = threadIdx.x, w = t >> 6, lane = t & 63;
  int wr = w >> 1, wc = w & 1;
  int quad = lane >> 4, l16 = lane & 15;
  const unsigned short* Bp = Bt + (size_t)jt * 32768;

  floatx4 acc[4][4];
  floatx4 z = {0.f, 0.f, 0.f, 0.f};
#pragma unroll
  for (int mi = 0; mi < 4; mi++)
#pragma unroll
    for (int ni = 0; ni < 4; ni++) acc[mi][ni] = z;

  for (int k0 = 0; k0 < 256; k0 += 64) {
    __syncthreads();
#pragma unroll
    for (int i = 0; i < 4; i++) {
      int rr = i * 32 + w * 8 + (lane >> 3);
      int c = (lane & 7) ^ (rr & 7);
      int gr = mt * 128 + rr;
      if (gr >= N_NODES) gr = N_NODES - 1;
      gll16(G + (size_t)gr * 768 + aoff + k0 + c * 8, Als + i * 4096 + w * 1024);
      gll16(Bp + (size_t)rr * 256 + k0 + c * 8, Bls + i * 4096 + w * 1024);
    }
    __syncthreads();  // drains vmcnt(0): LDS-DMA complete for all waves
#pragma unroll
    for (int ks = 0; ks < 2; ks++) {
      int cc = ks * 4 + quad;
      short8 a[4], b[4];
#pragma unroll
      for (int mi = 0; mi < 4; mi++) {
        int rr = wr * 64 + mi * 16 + l16;
        a[mi] = *(const short8*)(Als + rr * 128 + (cc ^ (rr & 7)) * 16);
      }
#pragma unroll
      for (int ni = 0; ni < 4; ni++) {
        int rr = wc * 64 + ni * 16 + l16;
        b[ni] = *(const short8*)(Bls + rr * 128 + (cc ^ (rr & 7)) * 16);
      }
#pragma unroll
      for (int mi = 0; mi < 4; mi++)
#pragma unroll
        for (int ni = 0; ni < 4; ni++)
          acc[mi][ni] = __builtin_amdgcn_mfma_f32_16x16x32_bf16(a[mi], b[ni], acc[mi][ni], 0, 0, 0);
    }
  }
#pragma unroll
  for (int mi = 0; mi < 4; mi++)
#pragma unroll
    for (int ni = 0; ni < 4; ni++) {
      int gc = jt * 128 + wc * 64 + ni * 16 + l16;
#pragma unroll
      for (int reg = 0; reg < 4; reg++) {
        int gr = mt * 128 + wr * 64 + mi * 16 + quad * 4 + reg;
        if (gr < N_NODES) T[(size_t)gr * TC + gc] = f2bf(acc[mi][ni][reg]);
      }
    }
}

// ---------------- epilogue: Ex_relu + gamma-weighted combine ----------------
__global__ void k_final(const unsigned short* __restrict__ T, const float* __restrict__ gamma,
                        const float* __restrict__ sArr, const float* __restrict__ bias,
                        float* __restrict__ out) {
  int t = threadIdx.x;
  int node = blockIdx.x * 4 + (t >> 6);
  if (node >= N_NODES) return;
  int lane = t & 63;
  int o0 = 2 * lane;
  float g[K_MIX];
#pragma unroll
  for (int k = 0; k < K_MIX; k++) g[k] = gamma[node * K_MIX + k];
  float sv = sArr[node];
  float b0 = bias[o0], b1 = bias[o0 + 1];
  const unsigned short* Tr = T + (size_t)node * TC;
  unsigned int c0u = *(const unsigned int*)(Tr + o0);
  float cx0 = bf2f(c0u), cx1 = bf2f(c0u >> 16);
  float a0 = 0.f, a1 = 0.f;
#pragma unroll
  for (int k = 0; k < K_MIX; k++) {
    unsigned int tm = *(const unsigned int*)(Tr + 128 * (1 + k) + o0);
    unsigned int tv = *(const unsigned int*)(Tr + 128 * (6 + k) + o0);
    float mu0 = cx0 + bf2f(tm) + b0 * sv;
    float mu1 = cx1 + bf2f(tm >> 16) + b1 * sv;
    a0 += g[k] * exrelu(mu0, bf2f(tv));
    a1 += g[k] * exrelu(mu1, bf2f(tv >> 16));
  }
  float2 ov = {a0, a1};
  *(float2*)(out + (size_t)node * OUT_F + o0) = ov;
}

extern "C" void kernel_launch(void* const* d_in, const int* in_sizes, int n_in,
                              void* d_out, int out_size, void* d_ws, size_t ws_size,
                              hipStream_t stream) {
  const float* x = (const float*)d_in[0];
  const int* ei = (const int*)d_in[1];
  const float* logp = (const float*)d_in[2];
  const float* means = (const float*)d_in[3];
  const float* lvar = (const float*)d_in[4];
  const float* W = (const float*)d_in[5];
  const float* bias = (const float*)d_in[6];
  float* out = (float*)d_out;
  const int* row = ei;
  const int* col = ei + N_EDGES;

  char* p = (char*)d_ws;
  auto alloc = [&](size_t bytes) -> char* {
    char* q = p;
    p += (bytes + 255) & ~((size_t)255);
    return q;
  };
  int* cursor = (int*)alloc(N_NODES * 4);                 // becomes deg
  int* bucket = (int*)alloc((size_t)N_NODES * BSTRIDE * 4);
  float* gamma = (float*)alloc((size_t)N_NODES * K_MIX * 4);
  float* sArr = (float*)alloc(N_NODES * 4);
  unsigned short* Bt = (unsigned short*)alloc((size_t)NT * 128 * 256 * 2);
  unsigned short* X0 = (unsigned short*)alloc((size_t)N_NODES * IN_F * 2);
  unsigned short* G = (unsigned short*)alloc((size_t)N_NODES * 768 * 2);
  unsigned short* T = (unsigned short*)alloc((size_t)N_NODES * TC * 2);

  hipMemsetAsync(cursor, 0, N_NODES * 4, stream);
  k_scatter<<<(N_EDGES + 255) / 256, 256, 0, stream>>>(row, col, cursor, bucket);
  k_buildB<<<(NT * 128 * 256) / 256, 256, 0, stream>>>(W, means, lvar, Bt);
  k_prepx<<<N_NODES / 4, 256, 0, stream>>>(x, logp, means, lvar, X0, gamma);
  k_spmm<<<N_NODES / 4, 256, 0, stream>>>(X0, cursor, bucket, G, sArr);
  k_gemm<<<GEMM_WGS, 256, 0, stream>>>(G, Bt, T);
  k_final<<<N_NODES / 4, 256, 0, stream>>>(T, gamma, sArr, bias, out);
}